// Round 2
// baseline (289.407 us; speedup 1.0000x reference)
//
#include <hip/hip_runtime.h>

typedef unsigned short u16;
typedef unsigned int u32;
typedef __bf16 bf16x8 __attribute__((ext_vector_type(8)));
typedef float f32x4 __attribute__((ext_vector_type(4)));

#define N_NODES 10000
#define N_EDGES 160000
#define D_IN 512
#define D_HID 1024

__device__ __forceinline__ u16 f2bf(float f) {
    union { float f; u32 u; } v; v.f = f;
    return (u16)((v.u + 0x7fffu + ((v.u >> 16) & 1u)) >> 16);
}
__device__ __forceinline__ float b2f(u32 h) {
    union { u32 u; float f; } v; v.u = h << 16; return v.f;
}

// ---- CSR build: histogram of dst ----
__global__ void hist_k(const int* __restrict__ dst, int* __restrict__ counts) {
    int e = blockIdx.x * 256 + threadIdx.x;
    if (e < N_EDGES) atomicAdd(&counts[dst[e]], 1);
}

// ---- single-block scan via wave shuffles: offs[10001], cursor[10000] ----
__global__ __launch_bounds__(1024) void scan_k(const int* __restrict__ counts,
                                               int* __restrict__ offs,
                                               int* __restrict__ cursor) {
    __shared__ int wpre[16];
    int t = threadIdx.x, l = t & 63, w = t >> 6;
    int base = t * 10;
    int c[10];
    int lsum = 0;
#pragma unroll
    for (int i = 0; i < 10; i++) {
        int idx = base + i;
        c[i] = (idx < N_NODES) ? counts[idx] : 0;
        lsum += c[i];
    }
    // wave-inclusive scan of lsum
    int sc = lsum;
#pragma unroll
    for (int d = 1; d < 64; d <<= 1) {
        int v = __shfl_up(sc, d);
        if (l >= d) sc += v;
    }
    __shared__ int wsum[16];
    if (l == 63) wsum[w] = sc;
    __syncthreads();
    if (w == 0 && l < 16) {
        int v = wsum[l];
        int p = v;
#pragma unroll
        for (int d = 1; d < 16; d <<= 1) {
            int u = __shfl_up(p, d);
            if (l >= d) p += u;
        }
        wpre[l] = p - v;
    }
    __syncthreads();
    int run = wpre[w] + sc - lsum;   // exclusive prefix for this thread's chunk
#pragma unroll
    for (int i = 0; i < 10; i++) {
        int idx = base + i;
        if (idx < N_NODES) { offs[idx] = run; cursor[idx] = run; run += c[i]; }
    }
    if (t == 1023) offs[N_NODES] = wpre[15] + sc;
}

// ---- reorder edges into dst-sorted order ----
__global__ void reorder_k(const int* __restrict__ src, const int* __restrict__ dst,
                          int* __restrict__ cursor, int* __restrict__ ssrc) {
    int e = blockIdx.x * 256 + threadIdx.x;
    if (e >= N_EDGES) return;
    int d = dst[e];
    int pos = atomicAdd(&cursor[d], 1);
    ssrc[pos] = src[e];
}

// ---- fp32 -> bf16 convert (feat copy), 8 elems/thread ----
__global__ void cvt_bf16_k(const float* __restrict__ in, u16* __restrict__ out, int n) {
    int i = (blockIdx.x * 256 + threadIdx.x) * 8;
    if (i >= n) return;
    float4 a = *(const float4*)(in + i);
    float4 b = *(const float4*)(in + i + 4);
    uint4 o;
    o.x = (u32)f2bf(a.x) | ((u32)f2bf(a.y) << 16);
    o.y = (u32)f2bf(a.z) | ((u32)f2bf(a.w) << 16);
    o.z = (u32)f2bf(b.x) | ((u32)f2bf(b.y) << 16);
    o.w = (u32)f2bf(b.z) | ((u32)f2bf(b.w) << 16);
    *(uint4*)(out + i) = o;
}

// ---- fused W1/W2 transpose+convert: WT[n][k] = bf16(W[k][n]) ----
__global__ void transw_k(const float* __restrict__ W1, u16* __restrict__ w1t,
                         const float* __restrict__ W2, u16* __restrict__ w2t) {
    __shared__ float tile[32][33];
    int b = blockIdx.x;
    const float* W; u16* WT; int K, N, nt;
    if (b < 512) { W = W1; WT = w1t; K = D_IN;  N = D_HID; nt = 32; }
    else         { b -= 512; W = W2; WT = w2t; K = D_HID; N = D_IN;  nt = 16; }
    int n0 = (b % nt) * 32, k0 = (b / nt) * 32;
    int tx = threadIdx.x, ty = threadIdx.y;
#pragma unroll
    for (int i = 0; i < 32; i += 8)
        tile[ty + i][tx] = W[(size_t)(k0 + ty + i) * N + n0 + tx];
    __syncthreads();
#pragma unroll
    for (int i = 0; i < 32; i += 8)
        WT[(size_t)(n0 + ty + i) * K + k0 + tx] = f2bf(tile[tx][ty + i]);
}

// ---- gather-sum from bf16 feat + (1+eps)*fp32 self, write bf16 ----
// one wave (64 lanes) per node, 8 bf16 per lane
__global__ __launch_bounds__(128) void gather_k(const float* __restrict__ feat,
                                                const u16* __restrict__ featb,
                                                const float* __restrict__ eps,
                                                const int* __restrict__ offs,
                                                const int* __restrict__ ssrc,
                                                u16* __restrict__ out) {
    int n = (blockIdx.x * 128 + threadIdx.x) >> 6;
    int l = threadIdx.x & 63;
    if (n >= N_NODES) return;
    int beg = offs[n], end = offs[n + 1];
    float s = 1.0f + eps[0];
    float4 s0 = *(const float4*)(feat + (size_t)n * D_IN + l * 8);
    float4 s1 = *(const float4*)(feat + (size_t)n * D_IN + l * 8 + 4);
    float acc[8] = { s * s0.x, s * s0.y, s * s0.z, s * s0.w,
                     s * s1.x, s * s1.y, s * s1.z, s * s1.w };
    int e = beg;
    for (; e + 4 <= end; e += 4) {
        int i0 = ssrc[e], i1 = ssrc[e + 1], i2 = ssrc[e + 2], i3 = ssrc[e + 3];
        uint4 v0 = *(const uint4*)(featb + (size_t)i0 * D_IN + l * 8);
        uint4 v1 = *(const uint4*)(featb + (size_t)i1 * D_IN + l * 8);
        uint4 v2 = *(const uint4*)(featb + (size_t)i2 * D_IN + l * 8);
        uint4 v3 = *(const uint4*)(featb + (size_t)i3 * D_IN + l * 8);
#define ACC4(v) \
        acc[0] += b2f(v.x & 0xffffu); acc[1] += b2f(v.x >> 16); \
        acc[2] += b2f(v.y & 0xffffu); acc[3] += b2f(v.y >> 16); \
        acc[4] += b2f(v.z & 0xffffu); acc[5] += b2f(v.z >> 16); \
        acc[6] += b2f(v.w & 0xffffu); acc[7] += b2f(v.w >> 16);
        ACC4(v0) ACC4(v1) ACC4(v2) ACC4(v3)
    }
    for (; e < end; e++) {
        int i0 = ssrc[e];
        uint4 v0 = *(const uint4*)(featb + (size_t)i0 * D_IN + l * 8);
        ACC4(v0)
    }
#undef ACC4
    uint4 o;
    o.x = (u32)f2bf(acc[0]) | ((u32)f2bf(acc[1]) << 16);
    o.y = (u32)f2bf(acc[2]) | ((u32)f2bf(acc[3]) << 16);
    o.z = (u32)f2bf(acc[4]) | ((u32)f2bf(acc[5]) << 16);
    o.w = (u32)f2bf(acc[6]) | ((u32)f2bf(acc[7]) << 16);
    *(uint4*)(out + (size_t)n * D_IN + l * 8) = o;
}

// ---- GEMM: C[M,N] = A[M,K] @ B[K,N]; A bf16 row-major, BT bf16 [N,K] ----
// 128x128 tile, BK=64, 256 thr (4 waves 2x2), 16x16x32 bf16 MFMA.
// REG-STAGED pipeline (no global_load_lds): plain global_load_dwordx4 -> VGPR
// issued right after the barrier (flies during the MFMA phase), then
// ds_write_b128 with the XOR chunk swizzle applied on the LDS-WRITE side
// (slot c of row r holds global chunk c^(r&7) -- bit-identical LDS image to
// the previous gload_lds version, so fragment reads are unchanged).
// Rationale: round-0/round-1 both pinned at ~43us with per-k-iter cost ~8x
// HBM latency => the 8 global_load_lds were effectively serialized (LDS-dest
// alias conservatism forces vmcnt drains between them). Plain loads to regs
// cannot be serialized that way.
// XCD-chunked bijective blockIdx swizzle: the NX blocks sharing an A-panel
// run on ONE XCD's L2 instead of 8 (FETCH was 51MB vs ~11MB unique).
// EPI=0: C = bf16(relu(acc + bias));  EPI=1: C = acc + bias + feat (fp32)
template <int EPI>
__global__ __launch_bounds__(256, 2) void gemm_k(const u16* __restrict__ A,
                                                 const u16* __restrict__ BT,
                                                 const float* __restrict__ bias,
                                                 const float* __restrict__ feat,
                                                 void* __restrict__ Cout,
                                                 int M, int N, int K) {
    __shared__ __bf16 sA[2][128 * 64];
    __shared__ __bf16 sB[2][128 * 64];

    // ---- XCD-chunked bijective remap (m204): consecutive logical tiles
    // (same A row-panel, sweeping columns) land on the same XCD ----
    const int NX = gridDim.x;
    const int nwg = NX * gridDim.y;
    const int flat = blockIdx.y * NX + blockIdx.x;
    const int qq = nwg >> 3, rr8 = nwg & 7;
    const int xcd = flat & 7, idx = flat >> 3;
    const int L = (xcd < rr8 ? xcd * (qq + 1) : rr8 * (qq + 1) + (xcd - rr8) * qq) + idx;
    const int row0 = (L / NX) * 128;
    const int col0 = (L % NX) * 128;

    const int t = threadIdx.x;
    const int w = t >> 6, l = t & 63;
    const int wm = (w >> 1) * 64, wn = (w & 1) * 64;
    const int lr = l & 15;
    const int lq = l >> 4;

    // ---- staging setup: wave w stages tile rows w*32..w*32+31 of A and BT
    // (4 segs of 8 rows, one global_load_dwordx4 each). Global reads LINEAR:
    // lane l -> row seg*8 + (l>>3), k-chunk (l&7)*8 elems. ----
    const u16* pA[4];
    const u16* pB[4];
    u32 ldso[4];   // LDS byte offset for the swizzled ds_write
    {
        int rloc = w * 32 + (l >> 3);
        int gch8 = (l & 7) * 8;                       // linear global chunk
        int slot = ((l & 7) ^ (l >> 3)) * 8;          // swizzled LDS slot
#pragma unroll
        for (int q = 0; q < 4; q++) {
            int ar = row0 + rloc + q * 8; if (ar > M - 1) ar = M - 1;
            pA[q] = A + (size_t)ar * K + gch8;
            int br = col0 + rloc + q * 8;
            pB[q] = BT + (size_t)br * K + gch8;
            ldso[q] = (u32)(((rloc + q * 8) * 64 + slot) * 2);  // bytes
        }
    }
    // fragment-read swizzle: slot elem-offset for global chunk (lq + kk/8)
    const int fo = ((lq ^ (lr & 7)) * 8);

    f32x4 acc[4][4] = {};
    uint4 stA[4], stB[4];

    const int NT = K >> 6;   // k-tiles of 64

    // ---- prologue: load tile 0 to regs, write to buf 0 ----
#pragma unroll
    for (int q = 0; q < 4; q++) {
        stA[q] = *(const uint4*)(pA[q]);
        stB[q] = *(const uint4*)(pB[q]);
    }
#pragma unroll
    for (int q = 0; q < 4; q++) {
        *(uint4*)((char*)(&sA[0][0]) + ldso[q]) = stA[q];
        *(uint4*)((char*)(&sB[0][0]) + ldso[q]) = stB[q];
    }

    for (int it = 0; it < NT; ++it) {
        __syncthreads();   // prev writes visible to all; prev reads done
        // issue next tile's global loads (async; fly during the MFMA phase)
        if (it + 1 < NT) {
            int kn = (it + 1) << 6;
#pragma unroll
            for (int q = 0; q < 4; q++) {
                stA[q] = *(const uint4*)(pA[q] + kn);
                stB[q] = *(const uint4*)(pB[q] + kn);
            }
        }
        // compute current tile from buf[it&1]
        const __bf16* cA = &sA[it & 1][0];
        const __bf16* cB = &sB[it & 1][0];
#pragma unroll
        for (int kk = 0; kk < 64; kk += 32) {
            const int fx = fo ^ kk;   // kk=32 flips chunk bit 2 (elem bit 5)
            bf16x8 fa[4], fb[4];
#pragma unroll
            for (int i = 0; i < 4; i++)
                fa[i] = *(const bf16x8*)(cA + (wm + i * 16 + lr) * 64 + fx);
#pragma unroll
            for (int j = 0; j < 4; j++)
                fb[j] = *(const bf16x8*)(cB + (wn + j * 16 + lr) * 64 + fx);
#pragma unroll
            for (int i = 0; i < 4; i++)
#pragma unroll
                for (int j = 0; j < 4; j++)
                    acc[i][j] = __builtin_amdgcn_mfma_f32_16x16x32_bf16(
                        fa[i], fb[j], acc[i][j], 0, 0, 0);
        }
        // write staged regs to the other buffer (compiler waits the loads)
        if (it + 1 < NT) {
            __bf16* nA = &sA[(it + 1) & 1][0];
            __bf16* nB = &sB[(it + 1) & 1][0];
#pragma unroll
            for (int q = 0; q < 4; q++) {
                *(uint4*)((char*)nA + ldso[q]) = stA[q];
                *(uint4*)((char*)nB + ldso[q]) = stB[q];
            }
        }
    }

#pragma unroll
    for (int i = 0; i < 4; i++) {
        int rowb = row0 + wm + i * 16 + lq * 4;
#pragma unroll
        for (int j = 0; j < 4; j++) {
            int col = col0 + wn + j * 16 + lr;
            float bv = bias[col];
#pragma unroll
            for (int r = 0; r < 4; r++) {
                int rr = rowb + r;
                if (rr < M) {
                    float v = acc[i][j][r] + bv;
                    if (EPI == 0) {
                        v = fmaxf(v, 0.0f);
                        ((u16*)Cout)[(size_t)rr * N + col] = f2bf(v);
                    } else {
                        v += feat[(size_t)rr * N + col];
                        ((float*)Cout)[(size_t)rr * N + col] = v;
                    }
                }
            }
        }
    }
}

extern "C" void kernel_launch(void* const* d_in, const int* in_sizes, int n_in,
                              void* d_out, int out_size, void* d_ws, size_t ws_size,
                              hipStream_t stream) {
    const float* feat = (const float*)d_in[0];
    const float* W1   = (const float*)d_in[1];
    const float* b1   = (const float*)d_in[2];
    const float* W2   = (const float*)d_in[3];
    const float* b2   = (const float*)d_in[4];
    const float* eps  = (const float*)d_in[5];
    const int*   src  = (const int*)d_in[6];
    const int*   dst  = (const int*)d_in[7];
    float* out = (float*)d_out;

    char* ws = (char*)d_ws;
    u16* rst_b16 = (u16*)(ws);                        // 10,240,000 B
    u16* h_b16   = (u16*)(ws + 10240000);             // 20,480,000 B
    u16* featb   = (u16*)(ws + 30720000);             // 10,240,000 B
    u16* w1t     = (u16*)(ws + 40960000);             //  1,048,576 B
    u16* w2t     = (u16*)(ws + 42008576);             //  1,048,576 B
    int* counts  = (int*)(ws + 43057152);             //     40,000 B
    int* offs    = (int*)(ws + 43097152);             //     40,004 B
    int* cursor  = (int*)(ws + 43137160);             //     40,000 B
    int* ssrc    = (int*)(ws + 43177160);             //    640,000 B

    const int NE = N_NODES * D_IN;  // 5,120,000

    hipMemsetAsync(counts, 0, N_NODES * sizeof(int), stream);
    hist_k<<<(N_EDGES + 255) / 256, 256, 0, stream>>>(dst, counts);
    scan_k<<<1, 1024, 0, stream>>>(counts, offs, cursor);
    reorder_k<<<(N_EDGES + 255) / 256, 256, 0, stream>>>(src, dst, cursor, ssrc);

    cvt_bf16_k<<<NE / 8 / 256, 256, 0, stream>>>(feat, featb, NE);
    transw_k<<<1024, dim3(32, 8), 0, stream>>>(W1, w1t, W2, w2t);

    gather_k<<<(N_NODES + 1) / 2, 128, 0, stream>>>(feat, featb, eps, offs, ssrc, rst_b16);

    const int MT = (N_NODES + 127) / 128;  // 79
    gemm_k<0><<<dim3(D_HID / 128, MT), 256, 0, stream>>>(rst_b16, w1t, b1, nullptr,
                                                         (void*)h_b16, N_NODES, D_HID, D_IN);
    gemm_k<1><<<dim3(D_IN / 128, MT), 256, 0, stream>>>(h_b16, w2t, b2, feat,
                                                        (void*)out, N_NODES, D_IN, D_HID);
}

// Round 3
// 228.903 us; speedup vs baseline: 1.2643x; 1.2643x over previous
//
#include <hip/hip_runtime.h>

typedef unsigned short u16;
typedef unsigned int u32;
typedef __bf16 bf16x8 __attribute__((ext_vector_type(8)));
typedef float f32x4 __attribute__((ext_vector_type(4)));

#define N_NODES 10000
#define N_EDGES 160000
#define D_IN 512
#define D_HID 1024

#define AS1 __attribute__((address_space(1)))
#define AS3 __attribute__((address_space(3)))

__device__ __forceinline__ u16 f2bf(float f) {
    union { float f; u32 u; } v; v.f = f;
    return (u16)((v.u + 0x7fffu + ((v.u >> 16) & 1u)) >> 16);
}
__device__ __forceinline__ float b2f(u32 h) {
    union { u32 u; float f; } v; v.u = h << 16; return v.f;
}

// ---- CSR build: histogram of dst ----
__global__ void hist_k(const int* __restrict__ dst, int* __restrict__ counts) {
    int e = blockIdx.x * 256 + threadIdx.x;
    if (e < N_EDGES) atomicAdd(&counts[dst[e]], 1);
}

// ---- single-block scan via wave shuffles: offs[10001], cursor[10000] ----
__global__ __launch_bounds__(1024) void scan_k(const int* __restrict__ counts,
                                               int* __restrict__ offs,
                                               int* __restrict__ cursor) {
    __shared__ int wpre[16];
    int t = threadIdx.x, l = t & 63, w = t >> 6;
    int base = t * 10;
    int c[10];
    int lsum = 0;
#pragma unroll
    for (int i = 0; i < 10; i++) {
        int idx = base + i;
        c[i] = (idx < N_NODES) ? counts[idx] : 0;
        lsum += c[i];
    }
    // wave-inclusive scan of lsum
    int sc = lsum;
#pragma unroll
    for (int d = 1; d < 64; d <<= 1) {
        int v = __shfl_up(sc, d);
        if (l >= d) sc += v;
    }
    __shared__ int wsum[16];
    if (l == 63) wsum[w] = sc;
    __syncthreads();
    if (w == 0 && l < 16) {
        int v = wsum[l];
        int p = v;
#pragma unroll
        for (int d = 1; d < 16; d <<= 1) {
            int u = __shfl_up(p, d);
            if (l >= d) p += u;
        }
        wpre[l] = p - v;
    }
    __syncthreads();
    int run = wpre[w] + sc - lsum;   // exclusive prefix for this thread's chunk
#pragma unroll
    for (int i = 0; i < 10; i++) {
        int idx = base + i;
        if (idx < N_NODES) { offs[idx] = run; cursor[idx] = run; run += c[i]; }
    }
    if (t == 1023) offs[N_NODES] = wpre[15] + sc;
}

// ---- reorder edges into dst-sorted order ----
__global__ void reorder_k(const int* __restrict__ src, const int* __restrict__ dst,
                          int* __restrict__ cursor, int* __restrict__ ssrc) {
    int e = blockIdx.x * 256 + threadIdx.x;
    if (e >= N_EDGES) return;
    int d = dst[e];
    int pos = atomicAdd(&cursor[d], 1);
    ssrc[pos] = src[e];
}

// ---- fp32 -> bf16 convert (feat copy), 8 elems/thread ----
__global__ void cvt_bf16_k(const float* __restrict__ in, u16* __restrict__ out, int n) {
    int i = (blockIdx.x * 256 + threadIdx.x) * 8;
    if (i >= n) return;
    float4 a = *(const float4*)(in + i);
    float4 b = *(const float4*)(in + i + 4);
    uint4 o;
    o.x = (u32)f2bf(a.x) | ((u32)f2bf(a.y) << 16);
    o.y = (u32)f2bf(a.z) | ((u32)f2bf(a.w) << 16);
    o.z = (u32)f2bf(b.x) | ((u32)f2bf(b.y) << 16);
    o.w = (u32)f2bf(b.z) | ((u32)f2bf(b.w) << 16);
    *(uint4*)(out + i) = o;
}

// ---- fused W1/W2 transpose+convert: WT[n][k] = bf16(W[k][n]) ----
__global__ void transw_k(const float* __restrict__ W1, u16* __restrict__ w1t,
                         const float* __restrict__ W2, u16* __restrict__ w2t) {
    __shared__ float tile[32][33];
    int b = blockIdx.x;
    const float* W; u16* WT; int K, N, nt;
    if (b < 512) { W = W1; WT = w1t; K = D_IN;  N = D_HID; nt = 32; }
    else         { b -= 512; W = W2; WT = w2t; K = D_HID; N = D_IN;  nt = 16; }
    int n0 = (b % nt) * 32, k0 = (b / nt) * 32;
    int tx = threadIdx.x, ty = threadIdx.y;
#pragma unroll
    for (int i = 0; i < 32; i += 8)
        tile[ty + i][tx] = W[(size_t)(k0 + ty + i) * N + n0 + tx];
    __syncthreads();
#pragma unroll
    for (int i = 0; i < 32; i += 8)
        WT[(size_t)(n0 + ty + i) * K + k0 + tx] = f2bf(tile[tx][ty + i]);
}

// ---- gather-sum from bf16 feat + (1+eps)*fp32 self, write bf16 ----
// one wave (64 lanes) per node, 8 bf16 per lane
__global__ __launch_bounds__(128) void gather_k(const float* __restrict__ feat,
                                                const u16* __restrict__ featb,
                                                const float* __restrict__ eps,
                                                const int* __restrict__ offs,
                                                const int* __restrict__ ssrc,
                                                u16* __restrict__ out) {
    int n = (blockIdx.x * 128 + threadIdx.x) >> 6;
    int l = threadIdx.x & 63;
    if (n >= N_NODES) return;
    int beg = offs[n], end = offs[n + 1];
    float s = 1.0f + eps[0];
    float4 s0 = *(const float4*)(feat + (size_t)n * D_IN + l * 8);
    float4 s1 = *(const float4*)(feat + (size_t)n * D_IN + l * 8 + 4);
    float acc[8] = { s * s0.x, s * s0.y, s * s0.z, s * s0.w,
                     s * s1.x, s * s1.y, s * s1.z, s * s1.w };
    int e = beg;
    for (; e + 4 <= end; e += 4) {
        int i0 = ssrc[e], i1 = ssrc[e + 1], i2 = ssrc[e + 2], i3 = ssrc[e + 3];
        uint4 v0 = *(const uint4*)(featb + (size_t)i0 * D_IN + l * 8);
        uint4 v1 = *(const uint4*)(featb + (size_t)i1 * D_IN + l * 8);
        uint4 v2 = *(const uint4*)(featb + (size_t)i2 * D_IN + l * 8);
        uint4 v3 = *(const uint4*)(featb + (size_t)i3 * D_IN + l * 8);
#define ACC4(v) \
        acc[0] += b2f(v.x & 0xffffu); acc[1] += b2f(v.x >> 16); \
        acc[2] += b2f(v.y & 0xffffu); acc[3] += b2f(v.y >> 16); \
        acc[4] += b2f(v.z & 0xffffu); acc[5] += b2f(v.z >> 16); \
        acc[6] += b2f(v.w & 0xffffu); acc[7] += b2f(v.w >> 16);
        ACC4(v0) ACC4(v1) ACC4(v2) ACC4(v3)
    }
    for (; e < end; e++) {
        int i0 = ssrc[e];
        uint4 v0 = *(const uint4*)(featb + (size_t)i0 * D_IN + l * 8);
        ACC4(v0)
    }
#undef ACC4
    uint4 o;
    o.x = (u32)f2bf(acc[0]) | ((u32)f2bf(acc[1]) << 16);
    o.y = (u32)f2bf(acc[2]) | ((u32)f2bf(acc[3]) << 16);
    o.z = (u32)f2bf(acc[4]) | ((u32)f2bf(acc[5]) << 16);
    o.w = (u32)f2bf(acc[6]) | ((u32)f2bf(acc[7]) << 16);
    *(uint4*)(out + (size_t)n * D_IN + l * 8) = o;
}

// ---- GEMM: C[M,N] = A[M,K] @ B[K,N]; A bf16 row-major, BT bf16 [N,K] ----
// 128x128 tile, BK=32, 4 waves (2x2), 16x16x32 bf16 MFMA, gload_lds staging
// (the proven-fast path; round-2's ds_write staging = 2.85M bank conflicts,
// 2.2x slower -> reverted).
// DEPTH-3 pipeline: 4 LDS buffers (4x16KB = 64KB -> 2 blocks/CU); tiles
// t+1,t+2,t+3 in flight while computing t. Counted s_waitcnt vmcnt(8)
// (4 loads/tile, 2 newer tiles allowed outstanding), one raw s_barrier/iter,
// sched_barrier(0) after the wait. Rationale: rounds 0/1 pinned at 43us,
// latency-bound (Mfma 8%, HBM 21%, all idle); depth-1 prefetch was null
// because compute/iter (~300cy) << load latency (~900cy) -- need depth>=3.
// LDS swizzle for BK=32: elem (row, g*8+e) at row*64B + (g^((row>>1)&3))*16B
// + e*2B; staging lane l in a 16-row instr carries global chunk
// g=(l&3)^((l>>3)&3) -- verified element-wise; bank-group occupancy
// isomorphic to round-0's measured-0-conflict pattern.
// XCD-chunked bijective remap kept from round-2 (FETCH 51->25MB measured).
// EPI=0: C = bf16(relu(acc + bias));  EPI=1: C = acc + bias + feat (fp32)
template <int EPI>
__global__ __launch_bounds__(256, 2) void gemm_k(const u16* __restrict__ A,
                                                 const u16* __restrict__ BT,
                                                 const float* __restrict__ bias,
                                                 const float* __restrict__ feat,
                                                 void* __restrict__ Cout,
                                                 int M, int N, int K) {
    __shared__ __bf16 sA[4][128 * 32];
    __shared__ __bf16 sB[4][128 * 32];

    // ---- XCD-chunked bijective remap (m204): consecutive logical tiles
    // (same A row-panel, sweeping columns) land on the same XCD ----
    const int NX = gridDim.x;
    const int nwg = NX * gridDim.y;
    const int flat = blockIdx.y * NX + blockIdx.x;
    const int qq = nwg >> 3, rr8 = nwg & 7;
    const int xcd = flat & 7, idx = flat >> 3;
    const int L = (xcd < rr8 ? xcd * (qq + 1) : rr8 * (qq + 1) + (xcd - rr8) * qq) + idx;
    const int row0 = (L / NX) * 128;
    const int col0 = (L % NX) * 128;

    const int t = threadIdx.x;
    const int w = t >> 6, l = t & 63;
    const int wm = (w >> 1) * 64, wn = (w & 1) * 64;
    const int lr = l & 15;
    const int lq = l >> 4;

    // ---- staging setup: wave w stages rows w*32..w*32+31 (2 instrs of 16
    // rows each, per matrix). Lane l -> row R+(l>>2), global k-chunk
    // g=(l&3)^((l>>3)&3) (pre-swizzled global source; LDS dest linear). ----
    const u16* pA[2];
    const u16* pB[2];
    int ldo[2];   // wave-uniform LDS elem offset
    {
        int g8 = (((l & 3) ^ ((l >> 3) & 3)) * 8);
        int rl = l >> 2;
#pragma unroll
        for (int h = 0; h < 2; h++) {
            int R = w * 32 + h * 16;
            int ar = row0 + R + rl; if (ar > M - 1) ar = M - 1;
            pA[h] = A + (size_t)ar * K + g8;
            int br = col0 + R + rl;
            pB[h] = BT + (size_t)br * K + g8;
            ldo[h] = R * 32;
        }
    }
    // fragment-read slot: lane (lr,lq) reads chunk lq of row ..+lr at slot
    // lq ^ ((row>>1)&3); (row>>1)&3 == (lr>>1)&3 since wm, i*16 are 0 mod 8
    const int fo = ((lq ^ ((lr >> 1) & 3)) * 8);

    f32x4 acc[4][4] = {};
    const int NT = K >> 5;   // k-tiles of 32

    auto STAGE = [&](int buf, int kt) {
        const int ko = kt << 5;
#pragma unroll
        for (int h = 0; h < 2; h++) {
            __builtin_amdgcn_global_load_lds((const AS1 void*)(pA[h] + ko),
                                             (AS3 void*)(&sA[buf][ldo[h]]), 16, 0, 0);
            __builtin_amdgcn_global_load_lds((const AS1 void*)(pB[h] + ko),
                                             (AS3 void*)(&sB[buf][ldo[h]]), 16, 0, 0);
        }
    };

    // prologue: fill pipeline 3 deep (12 loads in flight per wave)
    STAGE(0, 0);
    STAGE(1, 1);
    STAGE(2, 2);

    for (int it = 0; it < NT; ++it) {
        // wait tile it's 4 loads (tiles it+1, it+2 = 8 stay in flight)
        asm volatile("s_waitcnt vmcnt(8)" ::: "memory");
        __builtin_amdgcn_sched_barrier(0);
        __builtin_amdgcn_s_barrier();   // all waves' tile-it data in LDS;
                                        // also: all waves done reading buf
                                        // (it-1)&3 == (it+3)&3 -> safe target
        int kt = it + 3;
        STAGE((it + 3) & 3, kt < NT ? kt : 0);   // dummy restage in tail keeps
                                                 // vmcnt arithmetic uniform
        const __bf16* cA = &sA[it & 3][0];
        const __bf16* cB = &sB[it & 3][0];
        bf16x8 fa[4], fb[4];
#pragma unroll
        for (int i = 0; i < 4; i++)
            fa[i] = *(const bf16x8*)(cA + (wm + i * 16 + lr) * 32 + fo);
#pragma unroll
        for (int j = 0; j < 4; j++)
            fb[j] = *(const bf16x8*)(cB + (wn + j * 16 + lr) * 32 + fo);
#pragma unroll
        for (int i = 0; i < 4; i++)
#pragma unroll
            for (int j = 0; j < 4; j++)
                acc[i][j] = __builtin_amdgcn_mfma_f32_16x16x32_bf16(
                    fa[i], fb[j], acc[i][j], 0, 0, 0);
    }

#pragma unroll
    for (int i = 0; i < 4; i++) {
        int rowb = row0 + wm + i * 16 + lq * 4;
#pragma unroll
        for (int j = 0; j < 4; j++) {
            int col = col0 + wn + j * 16 + lr;
            float bv = bias[col];
#pragma unroll
            for (int r = 0; r < 4; r++) {
                int rr = rowb + r;
                if (rr < M) {
                    float v = acc[i][j][r] + bv;
                    if (EPI == 0) {
                        v = fmaxf(v, 0.0f);
                        ((u16*)Cout)[(size_t)rr * N + col] = f2bf(v);
                    } else {
                        v += feat[(size_t)rr * N + col];
                        ((float*)Cout)[(size_t)rr * N + col] = v;
                    }
                }
            }
        }
    }
}

extern "C" void kernel_launch(void* const* d_in, const int* in_sizes, int n_in,
                              void* d_out, int out_size, void* d_ws, size_t ws_size,
                              hipStream_t stream) {
    const float* feat = (const float*)d_in[0];
    const float* W1   = (const float*)d_in[1];
    const float* b1   = (const float*)d_in[2];
    const float* W2   = (const float*)d_in[3];
    const float* b2   = (const float*)d_in[4];
    const float* eps  = (const float*)d_in[5];
    const int*   src  = (const int*)d_in[6];
    const int*   dst  = (const int*)d_in[7];
    float* out = (float*)d_out;

    char* ws = (char*)d_ws;
    u16* rst_b16 = (u16*)(ws);                        // 10,240,000 B
    u16* h_b16   = (u16*)(ws + 10240000);             // 20,480,000 B
    u16* featb   = (u16*)(ws + 30720000);             // 10,240,000 B
    u16* w1t     = (u16*)(ws + 40960000);             //  1,048,576 B
    u16* w2t     = (u16*)(ws + 42008576);             //  1,048,576 B
    int* counts  = (int*)(ws + 43057152);             //     40,000 B
    int* offs    = (int*)(ws + 43097152);             //     40,004 B
    int* cursor  = (int*)(ws + 43137160);             //     40,000 B
    int* ssrc    = (int*)(ws + 43177160);             //    640,000 B

    const int NE = N_NODES * D_IN;  // 5,120,000

    hipMemsetAsync(counts, 0, N_NODES * sizeof(int), stream);
    hist_k<<<(N_EDGES + 255) / 256, 256, 0, stream>>>(dst, counts);
    scan_k<<<1, 1024, 0, stream>>>(counts, offs, cursor);
    reorder_k<<<(N_EDGES + 255) / 256, 256, 0, stream>>>(src, dst, cursor, ssrc);

    cvt_bf16_k<<<NE / 8 / 256, 256, 0, stream>>>(feat, featb, NE);
    transw_k<<<1024, dim3(32, 8), 0, stream>>>(W1, w1t, W2, w2t);

    gather_k<<<(N_NODES + 1) / 2, 128, 0, stream>>>(feat, featb, eps, offs, ssrc, rst_b16);

    const int MT = (N_NODES + 127) / 128;  // 79
    gemm_k<0><<<dim3(D_HID / 128, MT), 256, 0, stream>>>(rst_b16, w1t, b1, nullptr,
                                                         (void*)h_b16, N_NODES, D_HID, D_IN);
    gemm_k<1><<<dim3(D_IN / 128, MT), 256, 0, stream>>>(h_b16, w2t, b2, feat,
                                                        (void*)out, N_NODES, D_IN, D_HID);
}

// Round 4
// 198.901 us; speedup vs baseline: 1.4550x; 1.1508x over previous
//
#include <hip/hip_runtime.h>

typedef unsigned short u16;
typedef unsigned int u32;
typedef __bf16 bf16x8 __attribute__((ext_vector_type(8)));
typedef float f32x4 __attribute__((ext_vector_type(4)));

#define N_NODES 10000
#define N_EDGES 160000
#define D_IN 512
#define D_HID 1024

#define AS1 __attribute__((address_space(1)))
#define AS3 __attribute__((address_space(3)))

__device__ __forceinline__ u16 f2bf(float f) {
    union { float f; u32 u; } v; v.f = f;
    return (u16)((v.u + 0x7fffu + ((v.u >> 16) & 1u)) >> 16);
}
__device__ __forceinline__ float b2f(u32 h) {
    union { u32 u; float f; } v; v.u = h << 16; return v.f;
}

// ---- CSR build: histogram of dst ----
__global__ void hist_k(const int* __restrict__ dst, int* __restrict__ counts) {
    int e = blockIdx.x * 256 + threadIdx.x;
    if (e < N_EDGES) atomicAdd(&counts[dst[e]], 1);
}

// ---- single-block scan via wave shuffles: offs[10001], cursor[10000] ----
__global__ __launch_bounds__(1024) void scan_k(const int* __restrict__ counts,
                                               int* __restrict__ offs,
                                               int* __restrict__ cursor) {
    __shared__ int wpre[16];
    int t = threadIdx.x, l = t & 63, w = t >> 6;
    int base = t * 10;
    int c[10];
    int lsum = 0;
#pragma unroll
    for (int i = 0; i < 10; i++) {
        int idx = base + i;
        c[i] = (idx < N_NODES) ? counts[idx] : 0;
        lsum += c[i];
    }
    // wave-inclusive scan of lsum
    int sc = lsum;
#pragma unroll
    for (int d = 1; d < 64; d <<= 1) {
        int v = __shfl_up(sc, d);
        if (l >= d) sc += v;
    }
    __shared__ int wsum[16];
    if (l == 63) wsum[w] = sc;
    __syncthreads();
    if (w == 0 && l < 16) {
        int v = wsum[l];
        int p = v;
#pragma unroll
        for (int d = 1; d < 16; d <<= 1) {
            int u = __shfl_up(p, d);
            if (l >= d) p += u;
        }
        wpre[l] = p - v;
    }
    __syncthreads();
    int run = wpre[w] + sc - lsum;   // exclusive prefix for this thread's chunk
#pragma unroll
    for (int i = 0; i < 10; i++) {
        int idx = base + i;
        if (idx < N_NODES) { offs[idx] = run; cursor[idx] = run; run += c[i]; }
    }
    if (t == 1023) offs[N_NODES] = wpre[15] + sc;
}

// ---- reorder edges into dst-sorted order ----
__global__ void reorder_k(const int* __restrict__ src, const int* __restrict__ dst,
                          int* __restrict__ cursor, int* __restrict__ ssrc) {
    int e = blockIdx.x * 256 + threadIdx.x;
    if (e >= N_EDGES) return;
    int d = dst[e];
    int pos = atomicAdd(&cursor[d], 1);
    ssrc[pos] = src[e];
}

// ---- fp32 -> bf16 convert (feat copy), 8 elems/thread ----
__global__ void cvt_bf16_k(const float* __restrict__ in, u16* __restrict__ out, int n) {
    int i = (blockIdx.x * 256 + threadIdx.x) * 8;
    if (i >= n) return;
    float4 a = *(const float4*)(in + i);
    float4 b = *(const float4*)(in + i + 4);
    uint4 o;
    o.x = (u32)f2bf(a.x) | ((u32)f2bf(a.y) << 16);
    o.y = (u32)f2bf(a.z) | ((u32)f2bf(a.w) << 16);
    o.z = (u32)f2bf(b.x) | ((u32)f2bf(b.y) << 16);
    o.w = (u32)f2bf(b.z) | ((u32)f2bf(b.w) << 16);
    *(uint4*)(out + i) = o;
}

// ---- fused W1/W2 transpose+convert: WT[n][k] = bf16(W[k][n]) ----
__global__ void transw_k(const float* __restrict__ W1, u16* __restrict__ w1t,
                         const float* __restrict__ W2, u16* __restrict__ w2t) {
    __shared__ float tile[32][33];
    int b = blockIdx.x;
    const float* W; u16* WT; int K, N, nt;
    if (b < 512) { W = W1; WT = w1t; K = D_IN;  N = D_HID; nt = 32; }
    else         { b -= 512; W = W2; WT = w2t; K = D_HID; N = D_IN;  nt = 16; }
    int n0 = (b % nt) * 32, k0 = (b / nt) * 32;
    int tx = threadIdx.x, ty = threadIdx.y;
#pragma unroll
    for (int i = 0; i < 32; i += 8)
        tile[ty + i][tx] = W[(size_t)(k0 + ty + i) * N + n0 + tx];
    __syncthreads();
#pragma unroll
    for (int i = 0; i < 32; i += 8)
        WT[(size_t)(n0 + ty + i) * K + k0 + tx] = f2bf(tile[tx][ty + i]);
}

// ---- gather-sum from bf16 feat + (1+eps)*fp32 self, write bf16 ----
// one wave (64 lanes) per node, 8 bf16 per lane
__global__ __launch_bounds__(128) void gather_k(const float* __restrict__ feat,
                                                const u16* __restrict__ featb,
                                                const float* __restrict__ eps,
                                                const int* __restrict__ offs,
                                                const int* __restrict__ ssrc,
                                                u16* __restrict__ out) {
    int n = (blockIdx.x * 128 + threadIdx.x) >> 6;
    int l = threadIdx.x & 63;
    if (n >= N_NODES) return;
    int beg = offs[n], end = offs[n + 1];
    float s = 1.0f + eps[0];
    float4 s0 = *(const float4*)(feat + (size_t)n * D_IN + l * 8);
    float4 s1 = *(const float4*)(feat + (size_t)n * D_IN + l * 8 + 4);
    float acc[8] = { s * s0.x, s * s0.y, s * s0.z, s * s0.w,
                     s * s1.x, s * s1.y, s * s1.z, s * s1.w };
    int e = beg;
    for (; e + 4 <= end; e += 4) {
        int i0 = ssrc[e], i1 = ssrc[e + 1], i2 = ssrc[e + 2], i3 = ssrc[e + 3];
        uint4 v0 = *(const uint4*)(featb + (size_t)i0 * D_IN + l * 8);
        uint4 v1 = *(const uint4*)(featb + (size_t)i1 * D_IN + l * 8);
        uint4 v2 = *(const uint4*)(featb + (size_t)i2 * D_IN + l * 8);
        uint4 v3 = *(const uint4*)(featb + (size_t)i3 * D_IN + l * 8);
#define ACC4(v) \
        acc[0] += b2f(v.x & 0xffffu); acc[1] += b2f(v.x >> 16); \
        acc[2] += b2f(v.y & 0xffffu); acc[3] += b2f(v.y >> 16); \
        acc[4] += b2f(v.z & 0xffffu); acc[5] += b2f(v.z >> 16); \
        acc[6] += b2f(v.w & 0xffffu); acc[7] += b2f(v.w >> 16);
        ACC4(v0) ACC4(v1) ACC4(v2) ACC4(v3)
    }
    for (; e < end; e++) {
        int i0 = ssrc[e];
        uint4 v0 = *(const uint4*)(featb + (size_t)i0 * D_IN + l * 8);
        ACC4(v0)
    }
#undef ACC4
    uint4 o;
    o.x = (u32)f2bf(acc[0]) | ((u32)f2bf(acc[1]) << 16);
    o.y = (u32)f2bf(acc[2]) | ((u32)f2bf(acc[3]) << 16);
    o.z = (u32)f2bf(acc[4]) | ((u32)f2bf(acc[5]) << 16);
    o.w = (u32)f2bf(acc[6]) | ((u32)f2bf(acc[7]) << 16);
    *(uint4*)(out + (size_t)n * D_IN + l * 8) = o;
}

// ---- GEMM: C[M,N] = A[M,K] @ B[K,N]; A bf16 row-major, BT bf16 [N,K] ----
// 64x64 tile, ONE WAVE PER BLOCK (64 thr), BK=64, 16x16x32 bf16 MFMA.
// Theory (r0-r3 post-mortem): three schedules all pinned at 43-47us because
// 4-wave blocks are barrier-LOCKSTEPPED and the grid caps independent
// contexts at ~2.5 blocks/CU -- waves convoy, nothing covers the stalls.
// This version: NO barriers at all (single wave owns its LDS), grid 2512/1256
// blocks -> 4-5 independent waves/CU free-running (m114 overlap). K is a
// template param -> full unroll -> STATIC LDS buffer indices (compiler can
// prove sA[0]!=sA[1]; removes conservative-alias waitcnt risk).
// Per iter: vmcnt(0) for tile it (issued one full iter ago -> near-zero wait,
// L2-hot via XCD remap), ds_read frags, sched_barrier-pinned STAGE of tile
// it+1 (issued AFTER reads so any conservative wait covers only tile it),
// 32 MFMA. M-edge: last row-tile overlaps (row0=min(ry*64,M-64)); duplicate
// rows compute identical values -> benign double-store, zero clamping.
// Staging+read XOR swizzle identical to r0 (measured 0 bank conflicts).
// EPI=0: C = bf16(relu(acc + bias));  EPI=1: C = acc + bias + feat (fp32)
template <int EPI, int K>
__global__ __launch_bounds__(64) void gemm_k(const u16* __restrict__ A,
                                             const u16* __restrict__ BT,
                                             const float* __restrict__ bias,
                                             const float* __restrict__ feat,
                                             void* __restrict__ Cout,
                                             int M, int N) {
    __shared__ __bf16 sA[2][64 * 64];
    __shared__ __bf16 sB[2][64 * 64];

    // ---- XCD-chunked bijective remap (m204): consecutive logical tiles
    // (same A row-panel, sweeping columns) land on the same XCD ----
    const int NX = gridDim.x;
    const int nwg = NX * gridDim.y;
    const int flat = blockIdx.y * NX + blockIdx.x;
    const int qq = nwg >> 3, rr8 = nwg & 7;
    const int xcd = flat & 7, idx = flat >> 3;
    const int L = (xcd < rr8 ? xcd * (qq + 1) : rr8 * (qq + 1) + (xcd - rr8) * qq) + idx;
    int row0 = (L / NX) * 64;
    if (row0 > M - 64) row0 = M - 64;   // overlap last tile; dup rows benign
    const int col0 = (L % NX) * 64;

    const int l = threadIdx.x;
    const int lr = l & 15;
    const int lq = l >> 4;

    // ---- staging: seg q (0..7) covers rows q*8..q*8+7. Lane l -> row
    // q*8 + (l>>3), global k-chunk g=(l&7)^(l>>3) (pre-swizzled source;
    // LDS dest linear, wave-uniform base + lane*16B). ----
    const int g8 = (((l & 7) ^ (l >> 3)) * 8);
    const u16* bA = A  + (size_t)(row0 + (l >> 3)) * K + g8;
    const u16* bB = BT + (size_t)(col0 + (l >> 3)) * K + g8;
    // fragment-read slot: lane (lq,lr) reads chunk lq of row (..+lr) at slot
    // lq ^ (row&7) = lq ^ (lr&7)
    const int fo = ((lq ^ (lr & 7)) * 8);

    f32x4 acc[4][4] = {};
    const int NT = K >> 6;   // k-tiles of 64

#define STAGE(buf, kt)                                                         \
    {                                                                          \
        const int ko_ = (kt) << 6;                                             \
        _Pragma("unroll")                                                      \
        for (int q_ = 0; q_ < 8; q_++) {                                       \
            __builtin_amdgcn_global_load_lds(                                  \
                (const AS1 void*)(bA + (size_t)q_ * 8 * K + ko_),              \
                (AS3 void*)(&sA[buf][q_ * 512]), 16, 0, 0);                    \
            __builtin_amdgcn_global_load_lds(                                  \
                (const AS1 void*)(bB + (size_t)q_ * 8 * K + ko_),              \
                (AS3 void*)(&sB[buf][q_ * 512]), 16, 0, 0);                    \
        }                                                                      \
    }

    STAGE(0, 0);

#pragma unroll
    for (int it = 0; it < NT; ++it) {
        const int cur = it & 1;
        // tile it's 16 loads are the only outstanding VMEM ops here
        asm volatile("s_waitcnt vmcnt(0)" ::: "memory");
        __builtin_amdgcn_sched_barrier(0);
        bf16x8 fa[4], fb[4];
#pragma unroll
        for (int i = 0; i < 4; i++)
            fa[i] = *(const bf16x8*)(&sA[cur][0] + (i * 16 + lr) * 64 + (fo ^ 0));
#pragma unroll
        for (int j = 0; j < 4; j++)
            fb[j] = *(const bf16x8*)(&sB[cur][0] + (j * 16 + lr) * 64 + (fo ^ 0));
        bf16x8 fa2[4], fb2[4];
#pragma unroll
        for (int i = 0; i < 4; i++)
            fa2[i] = *(const bf16x8*)(&sA[cur][0] + (i * 16 + lr) * 64 + (fo ^ 32));
#pragma unroll
        for (int j = 0; j < 4; j++)
            fb2[j] = *(const bf16x8*)(&sB[cur][0] + (j * 16 + lr) * 64 + (fo ^ 32));
        __builtin_amdgcn_sched_barrier(0);
        // prefetch next tile into the other buffer: its target's reads
        // finished a full iteration ago; issued after this tile's ds_reads
        // so conservative compiler waits cannot couple it to this compute
        if (it + 1 < NT) STAGE(cur ^ 1, it + 1);
        __builtin_amdgcn_sched_barrier(0);
#pragma unroll
        for (int i = 0; i < 4; i++)
#pragma unroll
            for (int j = 0; j < 4; j++)
                acc[i][j] = __builtin_amdgcn_mfma_f32_16x16x32_bf16(
                    fa[i], fb[j], acc[i][j], 0, 0, 0);
#pragma unroll
        for (int i = 0; i < 4; i++)
#pragma unroll
            for (int j = 0; j < 4; j++)
                acc[i][j] = __builtin_amdgcn_mfma_f32_16x16x32_bf16(
                    fa2[i], fb2[j], acc[i][j], 0, 0, 0);
    }
#undef STAGE

#pragma unroll
    for (int i = 0; i < 4; i++) {
        int rowb = row0 + i * 16 + lq * 4;
#pragma unroll
        for (int j = 0; j < 4; j++) {
            int col = col0 + j * 16 + lr;
            float bv = bias[col];
#pragma unroll
            for (int r = 0; r < 4; r++) {
                int rr = rowb + r;
                float v = acc[i][j][r] + bv;
                if (EPI == 0) {
                    v = fmaxf(v, 0.0f);
                    ((u16*)Cout)[(size_t)rr * N + col] = f2bf(v);
                } else {
                    v += feat[(size_t)rr * N + col];
                    ((float*)Cout)[(size_t)rr * N + col] = v;
                }
            }
        }
    }
}

extern "C" void kernel_launch(void* const* d_in, const int* in_sizes, int n_in,
                              void* d_out, int out_size, void* d_ws, size_t ws_size,
                              hipStream_t stream) {
    const float* feat = (const float*)d_in[0];
    const float* W1   = (const float*)d_in[1];
    const float* b1   = (const float*)d_in[2];
    const float* W2   = (const float*)d_in[3];
    const float* b2   = (const float*)d_in[4];
    const float* eps  = (const float*)d_in[5];
    const int*   src  = (const int*)d_in[6];
    const int*   dst  = (const int*)d_in[7];
    float* out = (float*)d_out;

    char* ws = (char*)d_ws;
    u16* rst_b16 = (u16*)(ws);                        // 10,240,000 B
    u16* h_b16   = (u16*)(ws + 10240000);             // 20,480,000 B
    u16* featb   = (u16*)(ws + 30720000);             // 10,240,000 B
    u16* w1t     = (u16*)(ws + 40960000);             //  1,048,576 B
    u16* w2t     = (u16*)(ws + 42008576);             //  1,048,576 B
    int* counts  = (int*)(ws + 43057152);             //     40,000 B
    int* offs    = (int*)(ws + 43097152);             //     40,004 B
    int* cursor  = (int*)(ws + 43137160);             //     40,000 B
    int* ssrc    = (int*)(ws + 43177160);             //    640,000 B

    const int NE = N_NODES * D_IN;  // 5,120,000

    hipMemsetAsync(counts, 0, N_NODES * sizeof(int), stream);
    hist_k<<<(N_EDGES + 255) / 256, 256, 0, stream>>>(dst, counts);
    scan_k<<<1, 1024, 0, stream>>>(counts, offs, cursor);
    reorder_k<<<(N_EDGES + 255) / 256, 256, 0, stream>>>(src, dst, cursor, ssrc);

    cvt_bf16_k<<<NE / 8 / 256, 256, 0, stream>>>(feat, featb, NE);
    transw_k<<<1024, dim3(32, 8), 0, stream>>>(W1, w1t, W2, w2t);

    gather_k<<<(N_NODES + 1) / 2, 128, 0, stream>>>(feat, featb, eps, offs, ssrc, rst_b16);

    const int MT = (N_NODES + 63) / 64;  // 157 row-tiles (last one overlaps)
    gemm_k<0, D_IN><<<dim3(D_HID / 64, MT), 64, 0, stream>>>(
        rst_b16, w1t, b1, nullptr, (void*)h_b16, N_NODES, D_HID);
    gemm_k<1, D_HID><<<dim3(D_IN / 64, MT), 64, 0, stream>>>(
        h_b16, w2t, b2, feat, (void*)out, N_NODES, D_IN);
}